// Round 8
// baseline (271.011 us; speedup 1.0000x reference)
//
#include <hip/hip_runtime.h>
#include <hip/hip_bf16.h>

typedef __bf16 bf16x8 __attribute__((ext_vector_type(8)));
typedef float f32x4 __attribute__((ext_vector_type(4)));
typedef float f32x16 __attribute__((ext_vector_type(16)));
typedef unsigned short u16;

#define S_ 2048
#define D_ 2048
#define H_ 16
#define HD_ 128
#define SCALE_ 0.08838834764831845f   // 1/sqrt(128)

__device__ __forceinline__ u16 f2bf(float f) {
  unsigned u = __builtin_bit_cast(unsigned, f);
  u += 0x7fffu + ((u >> 16) & 1u);    // RNE
  return (u16)(u >> 16);
}

__device__ __forceinline__ void gload16(void* lds, const void* g) {
  __builtin_amdgcn_global_load_lds((const __attribute__((address_space(1))) void*)g,
                                   (__attribute__((address_space(3))) void*)lds, 16, 0, 0);
}

__device__ __forceinline__ f32x4 mfma16(bf16x8 a, bf16x8 b, f32x4 c) {
  return __builtin_amdgcn_mfma_f32_16x16x32_bf16(a, b, c, 0, 0, 0);
}
__device__ __forceinline__ f32x16 mfma32(bf16x8 a, bf16x8 b, f32x16 c) {
  return __builtin_amdgcn_mfma_f32_32x32x16_bf16(a, b, c, 0, 0, 0);
}

__device__ __forceinline__ unsigned cvt_pk_bf16(float lo, float hi) {
  unsigned r;
  asm("v_cvt_pk_bf16_f32 %0, %1, %2" : "=v"(r) : "v"(lo), "v"(hi));
  return r;
}

// ---------------- cast f32 -> bf16, vectorized ----------------
__global__ void k_cast_bf16(const float* __restrict__ in, u16* __restrict__ out, int n4) {
  int i = blockIdx.x * blockDim.x + threadIdx.x;
  if (i < n4) {
    float4 v = ((const float4*)in)[i];
    ushort4 o;
    o.x = f2bf(v.x); o.y = f2bf(v.y); o.z = f2bf(v.z); o.w = f2bf(v.w);
    ((ushort4*)out)[i] = o;
  }
}

// ------------- transpose + cast: in[rows][cols] f32 -> out[cols][rows] bf16 -------------
__global__ void k_transpose_cast(const float* __restrict__ in, u16* __restrict__ out,
                                 int rows, int cols) {
  __shared__ u16 tile[32][33];
  int c0 = blockIdx.x * 32, r0 = blockIdx.y * 32;
  int tx = threadIdx.x, ty = threadIdx.y;   // (32,8)
#pragma unroll
  for (int i = 0; i < 4; i++) {
    int r = r0 + ty + i * 8;
    tile[ty + i * 8][tx] = f2bf(in[(long)r * cols + c0 + tx]);
  }
  __syncthreads();
#pragma unroll
  for (int i = 0; i < 4; i++) {
    int c = c0 + ty + i * 8;
    out[(long)c * rows + r0 + tx] = tile[tx][ty + i * 8];
  }
}

// QKV scatter-store: Q -> qb[4096][2048]; K/V -> fragment-packed per-(bh,tile32) layouts
__device__ __forceinline__ void qkv_store(u16* __restrict__ qb, u16* __restrict__ kpk,
                                          u16* __restrict__ vpk, int row, int col, float val) {
  u16 o = f2bf(val);
  int h = col / 384;
  int m3 = col - h * 384;
  int b = row >> 11, s = row & 2047;
  int bh = b * 16 + h, t = s >> 5;
  if (m3 < 128) {
    qb[(long)row * 2048 + h * 128 + m3] = o;
  } else if (m3 < 256) {
    int dd = m3 - 128;
    long idx = ((((long)bh * 64 + t) * 8 + (dd >> 4)) * 64 + (((dd >> 3) & 1) << 5) + (s & 31)) * 8 + (dd & 7);
    kpk[idx] = o;
  } else {
    int dd = m3 - 256;
    long idx = ((((long)bh * 64 + t) * 8 + (((s >> 4) & 1) << 2) + (dd >> 5)) * 64 + (((s >> 3) & 1) << 5) + (dd & 31)) * 8 + (s & 7);
    vpk[idx] = o;
  }
}

// ------------- 8-phase 256x256 GEMM (m201 template): C = A[M][K]*Bt[N][K]^T + bias -------------
// 512 thr = 8 waves (2M x 4N), per-wave 128x64 out, BK=64.
// LDS 128 KB: lA[2 slot][2 half][128x64], lB same. chunk^(row&7) swizzle.
// 8 phases / 2 K-tiles; 1 half-tile staged per phase; counted vmcnt(4) at ph4/ph8.
// Stage order: A(t+1)@ph1,2  B(t+2)@ph3,4  A(t+2)@ph5,6  B(t+3)@ph7,8.
//   ph4 vmcnt(4): retires ...A1(t+1); leaves B(t+2) (4 ops) in flight -> slot1 valid for ph5-8.
//   ph8 vmcnt(4): retires ...A1(t+2); leaves B(t+3) -> slot0 valid for next ph1-4.
template <int MODE>   // 2: QKV scatter epilogue; 0: f32 out
__global__ __launch_bounds__(512) void k_gemm8(const u16* __restrict__ A,
                                               const u16* __restrict__ Bt,
                                               const float* __restrict__ bias,
                                               void* __restrict__ Cv,
                                               int M, int N, int K, int NTM,
                                               u16* __restrict__ qb,
                                               u16* __restrict__ kpk,
                                               u16* __restrict__ vpk) {
  __shared__ __align__(16) u16 lA[2][2][128 * 64];
  __shared__ __align__(16) u16 lB[2][2][128 * 64];
  const int tid = threadIdx.x, w = tid >> 6, l = tid & 63;
  const int wm = w >> 2, wn = w & 3, lr = l & 15, lg = l >> 4;
  const int nwg = NTM * (N >> 8);
  const int per = nwg >> 3;                     // nwg % 8 == 0
  const int wgid = ((int)blockIdx.x & 7) * per + ((int)blockIdx.x >> 3);
  const int tm = (wgid % NTM) << 8;
  const int tn = (wgid / NTM) << 8;
  const int NT = K >> 6;                        // assumed even

  f32x4 acc[8][4];
#pragma unroll
  for (int m = 0; m < 8; m++)
#pragma unroll
    for (int n = 0; n < 4; n++) acc[m][n] = {0.f, 0.f, 0.f, 0.f};

  // stage one 128-row half (16 KB): 2 gload16 per thread
  auto stageAh = [&](int kt, int hf) {
    int s = kt & 1;
#pragma unroll
    for (int i = 0; i < 2; i++) {
      int f = i * 512 + tid, r = f >> 3, cg = (f & 7) ^ (r & 7);
      gload16(&lA[s][hf][(i * 512 + w * 64) * 8],
              &A[(long)(tm + hf * 128 + r) * K + kt * 64 + cg * 8]);
    }
  };
  auto stageBh = [&](int kt, int hf) {
    int s = kt & 1;
#pragma unroll
    for (int i = 0; i < 2; i++) {
      int f = i * 512 + tid, r = f >> 3, cg = (f & 7) ^ (r & 7);
      gload16(&lB[s][hf][(i * 512 + w * 64) * 8],
              &Bt[(long)(tn + hf * 128 + r) * K + kt * 64 + cg * 8]);
    }
  };

  // prologue: A(0),B(0),B(1) staged; wait tile0 (allow B(1)'s 4 ops in flight)
  stageAh(0, 0); stageAh(0, 1);
  stageBh(0, 0); stageBh(0, 1);
  if (NT > 1) { stageBh(1, 0); stageBh(1, 1); }
  asm volatile("s_waitcnt vmcnt(4)" ::: "memory");
  __builtin_amdgcn_s_barrier();

  // one half-iteration = 4 phases computing tile in slot s
  auto half_iter = [&](int s, int ktA, bool gA, int ktB, bool gB) {
    bf16x8 aL[4][2], aH[4][2], b01[2][2], b23[2][2];
    // ---- ph A: read aL + b01; stage A(ktA) half0; MFMA Q0 ----
#pragma unroll
    for (int m = 0; m < 4; m++)
#pragma unroll
      for (int k = 0; k < 2; k++) {
        int rr = m * 16 + lr;
        aL[m][k] = *(const bf16x8*)&lA[s][wm][rr * 64 + ((((k << 2) + lg) ^ (rr & 7)) << 3)];
      }
#pragma unroll
    for (int n = 0; n < 2; n++)
#pragma unroll
      for (int k = 0; k < 2; k++) {
        int rb = (wn & 1) * 64 + n * 16 + lr;
        b01[n][k] = *(const bf16x8*)&lB[s][wn >> 1][rb * 64 + ((((k << 2) + lg) ^ (rb & 7)) << 3)];
      }
    if (gA) stageAh(ktA, 0);
    __builtin_amdgcn_s_barrier();
    asm volatile("s_waitcnt lgkmcnt(0)" ::: "memory");
    __builtin_amdgcn_sched_barrier(0);
    __builtin_amdgcn_s_setprio(1);
#pragma unroll
    for (int m = 0; m < 4; m++)
#pragma unroll
      for (int n = 0; n < 2; n++)
#pragma unroll
        for (int k = 0; k < 2; k++) acc[m][n] = mfma16(aL[m][k], b01[n][k], acc[m][n]);
    __builtin_amdgcn_s_setprio(0);
    __builtin_amdgcn_s_barrier();
    // ---- ph B: read b23; stage A(ktA) half1; MFMA Q1 ----
#pragma unroll
    for (int n = 0; n < 2; n++)
#pragma unroll
      for (int k = 0; k < 2; k++) {
        int rb = (wn & 1) * 64 + (n + 2) * 16 + lr;
        b23[n][k] = *(const bf16x8*)&lB[s][wn >> 1][rb * 64 + ((((k << 2) + lg) ^ (rb & 7)) << 3)];
      }
    if (gA) stageAh(ktA, 1);
    __builtin_amdgcn_s_barrier();
    asm volatile("s_waitcnt lgkmcnt(0)" ::: "memory");
    __builtin_amdgcn_sched_barrier(0);
    __builtin_amdgcn_s_setprio(1);
#pragma unroll
    for (int m = 0; m < 4; m++)
#pragma unroll
      for (int n = 0; n < 2; n++)
#pragma unroll
        for (int k = 0; k < 2; k++) acc[m][n + 2] = mfma16(aL[m][k], b23[n][k], acc[m][n + 2]);
    __builtin_amdgcn_s_setprio(0);
    __builtin_amdgcn_s_barrier();
    // ---- ph C: read aH; stage B(ktB) half0; MFMA Q2 ----
#pragma unroll
    for (int m = 0; m < 4; m++)
#pragma unroll
      for (int k = 0; k < 2; k++) {
        int rr = 64 + m * 16 + lr;
        aH[m][k] = *(const bf16x8*)&lA[s][wm][rr * 64 + ((((k << 2) + lg) ^ (rr & 7)) << 3)];
      }
    if (gB) stageBh(ktB, 0);
    __builtin_amdgcn_s_barrier();
    asm volatile("s_waitcnt lgkmcnt(0)" ::: "memory");
    __builtin_amdgcn_sched_barrier(0);
    __builtin_amdgcn_s_setprio(1);
#pragma unroll
    for (int m = 0; m < 4; m++)
#pragma unroll
      for (int n = 0; n < 2; n++)
#pragma unroll
        for (int k = 0; k < 2; k++) acc[m + 4][n] = mfma16(aH[m][k], b01[n][k], acc[m + 4][n]);
    __builtin_amdgcn_s_setprio(0);
    __builtin_amdgcn_s_barrier();
    // ---- ph D: stage B(ktB) half1; counted vmcnt; MFMA Q3 ----
    if (gB) stageBh(ktB, 1);
    __builtin_amdgcn_s_barrier();
    if (gB) asm volatile("s_waitcnt vmcnt(4)" ::: "memory");
    else    asm volatile("s_waitcnt vmcnt(0)" ::: "memory");
    __builtin_amdgcn_sched_barrier(0);
    __builtin_amdgcn_s_setprio(1);
#pragma unroll
    for (int m = 0; m < 4; m++)
#pragma unroll
      for (int n = 0; n < 2; n++)
#pragma unroll
        for (int k = 0; k < 2; k++) acc[m + 4][n + 2] = mfma16(aH[m][k], b23[n][k], acc[m + 4][n + 2]);
    __builtin_amdgcn_s_setprio(0);
    __builtin_amdgcn_s_barrier();
  };

  for (int j = 0; j < (NT >> 1); ++j) {
    const int t = 2 * j;
    const bool g2 = (t + 2 < NT), g3 = (t + 3 < NT);
    half_iter(0, t + 1, true, t + 2, g2);   // tile t   from slot0
    half_iter(1, t + 2, g2,   t + 3, g3);   // tile t+1 from slot1
  }

  // epilogue
#pragma unroll
  for (int n = 0; n < 4; n++) {
    int col = tn + wn * 64 + n * 16 + lr;
    float bv = bias[col];
#pragma unroll
    for (int m = 0; m < 8; m++) {
      int row0 = tm + wm * 128 + m * 16 + lg * 4;
#pragma unroll
      for (int j = 0; j < 4; j++) {
        float v = acc[m][n][j] + bv;
        if constexpr (MODE == 2)
          qkv_store(qb, kpk, vpk, row0 + j, col, v);
        else
          ((float*)Cv)[(long)(row0 + j) * N + col] = v;
      }
    }
  }
}

// ------------- 2-phase GEMM (dense projection): C[M][N] = A*Bt^T + bias, f32 out -------------
__global__ __launch_bounds__(512) void k_gemm2(const u16* __restrict__ A,
                                               const u16* __restrict__ Bt,
                                               const float* __restrict__ bias,
                                               float* __restrict__ Cv,
                                               int M, int N, int K, int NTM) {
  __shared__ __align__(16) u16 lA[2][256 * 64];
  __shared__ __align__(16) u16 lB[2][128 * 64];
  const int tid = threadIdx.x, w = tid >> 6, l = tid & 63;
  const int wr = w >> 1, wc = w & 1, lr = l & 15, lg = l >> 4;
  const int nwg = NTM * (N >> 7);
  const int per = nwg >> 3;
  const int wgid = ((int)blockIdx.x & 7) * per + ((int)blockIdx.x >> 3);
  const int tm = (wgid % NTM) << 8;
  const int tn = (wgid / NTM) << 7;
  const int NT = K >> 6;

  f32x4 acc[4][4];
#pragma unroll
  for (int m = 0; m < 4; m++)
#pragma unroll
    for (int n = 0; n < 4; n++) acc[m][n] = {0.f, 0.f, 0.f, 0.f};

  auto stageA = [&](int buf, int kt) {
#pragma unroll
    for (int i = 0; i < 4; i++) {
      int base = i * 512 + w * 64;
      int fl = base + l, r = fl >> 3, cg = (fl & 7) ^ (r & 7);
      gload16(&lA[buf][base * 8], &A[(long)(tm + r) * K + kt * 64 + cg * 8]);
    }
  };
  auto stageB = [&](int buf, int kt) {
#pragma unroll
    for (int i = 0; i < 2; i++) {
      int base = i * 512 + w * 64;
      int fl = base + l, r = fl >> 3, cg = (fl & 7) ^ (r & 7);
      gload16(&lB[buf][base * 8], &Bt[(long)(tn + r) * K + kt * 64 + cg * 8]);
    }
  };

  stageA(0, 0);
  stageB(0, 0);
  if (NT > 1) stageA(1, 1);
  asm volatile("s_waitcnt vmcnt(4)" ::: "memory");
  __builtin_amdgcn_s_barrier();

  for (int kt = 0; kt < NT; ++kt) {
    const int b = kt & 1;
    bf16x8 af[4][2], bfr[2][2];
#pragma unroll
    for (int m = 0; m < 4; m++)
#pragma unroll
      for (int k = 0; k < 2; k++) {
        int r = wr * 64 + m * 16 + lr;
        af[m][k] = *(const bf16x8*)&lA[b][r * 64 + ((((k << 2) + lg) ^ (r & 7)) << 3)];
      }
#pragma unroll
    for (int n = 0; n < 2; n++)
#pragma unroll
      for (int k = 0; k < 2; k++) {
        int r = wc * 64 + n * 16 + lr;
        bfr[n][k] = *(const bf16x8*)&lB[b][r * 64 + ((((k << 2) + lg) ^ (r & 7)) << 3)];
      }
    if (kt + 1 < NT) stageB(b ^ 1, kt + 1);
    __builtin_amdgcn_s_barrier();
    asm volatile("s_waitcnt lgkmcnt(0)" ::: "memory");
    __builtin_amdgcn_sched_barrier(0);
    __builtin_amdgcn_s_setprio(1);
#pragma unroll
    for (int m = 0; m < 4; m++)
#pragma unroll
      for (int n = 0; n < 2; n++)
#pragma unroll
        for (int k = 0; k < 2; k++)
          acc[m][n] = mfma16(af[m][k], bfr[n][k], acc[m][n]);
    __builtin_amdgcn_s_setprio(0);
    __builtin_amdgcn_s_barrier();

#pragma unroll
    for (int n = 0; n < 2; n++)
#pragma unroll
      for (int k = 0; k < 2; k++) {
        int r = wc * 64 + (n + 2) * 16 + lr;
        bfr[n][k] = *(const bf16x8*)&lB[b][r * 64 + ((((k << 2) + lg) ^ (r & 7)) << 3)];
      }
    if (kt + 2 < NT) stageA(b, kt + 2);
    __builtin_amdgcn_s_barrier();
    if (kt + 2 < NT)
      asm volatile("s_waitcnt vmcnt(4) lgkmcnt(0)" ::: "memory");
    else
      asm volatile("s_waitcnt vmcnt(0) lgkmcnt(0)" ::: "memory");
    __builtin_amdgcn_sched_barrier(0);
    __builtin_amdgcn_s_setprio(1);
#pragma unroll
    for (int m = 0; m < 4; m++)
#pragma unroll
      for (int n = 0; n < 2; n++)
#pragma unroll
        for (int k = 0; k < 2; k++)
          acc[m][n + 2] = mfma16(af[m][k], bfr[n][k], acc[m][n + 2]);
    __builtin_amdgcn_s_setprio(0);
    __builtin_amdgcn_s_barrier();
  }

#pragma unroll
  for (int n = 0; n < 4; n++) {
    int col = tn + wc * 64 + n * 16 + lr;
    float bv = bias[col];
#pragma unroll
    for (int m = 0; m < 4; m++) {
      int row0 = tm + wr * 64 + m * 16 + lg * 4;
#pragma unroll
      for (int j = 0; j < 4; j++)
        Cv[(long)(row0 + j) * N + col] = acc[m][n][j] + bv;
    }
  }
}

// ------------- causal flash attention: independent waves, packed fragments, reg-dbuf -------------
__global__ __launch_bounds__(256, 2) void k_attn(const u16* __restrict__ qb,
                                                 const u16* __restrict__ kpk,
                                                 const u16* __restrict__ vpk,
                                                 const float* __restrict__ amask,
                                                 u16* __restrict__ ctx) {
  const int bh = blockIdx.x, b = bh >> 4, h = bh & 15;
  const int pr = blockIdx.y;
  const int tid = threadIdx.x, w = tid >> 6, l = tid & 63;
  const int lr5 = l & 31, hi = l >> 5;
  const int qrow0 = (w < 2) ? (pr * 64 + w * 32) : ((31 - pr) * 64 + (w - 2) * 32);
  const int nt = (qrow0 >> 5) + 1;

  bf16x8 qf[8];
  {
    const u16* qp = qb + (long)(b * S_ + qrow0 + lr5) * 2048 + h * HD_ + hi * 8;
#pragma unroll
    for (int ks = 0; ks < 8; ks++) qf[ks] = *(const bf16x8*)(qp + ks * 16);
  }

  f32x16 aO[4];
#pragma unroll
  for (int db = 0; db < 4; db++)
#pragma unroll
    for (int r = 0; r < 16; r++) aO[db][r] = 0.f;
  float mrun = -3.0e38f, lrun = 0.f;

  const u16* kbase = kpk + (long)bh * 64 * 8 * 512 + l * 8;
  const u16* vbase = vpk + (long)bh * 64 * 8 * 512 + l * 8;
  const float* ab0 = amask + b * S_;

  bf16x8 kA[8], kB[8];
#pragma unroll
  for (int f = 0; f < 8; f++) kA[f] = *(const bf16x8*)(kbase + f * 512);

  auto body = [&](bf16x8 (&cur)[8], bf16x8 (&nxt)[8], int t) {
    const int t32 = t << 5;
    bf16x8 vf[8];
    {
      const u16* vp = vbase + (long)t * 4096;
#pragma unroll
      for (int f = 0; f < 8; f++) vf[f] = *(const bf16x8*)(vp + f * 512);
    }
    f32x4 am[4];
#pragma unroll
    for (int rg = 0; rg < 4; rg++) am[rg] = *(const f32x4*)(ab0 + t32 + rg * 8 + hi * 4);

    f32x16 aS;
#pragma unroll
    for (int r = 0; r < 16; r++) aS[r] = 0.f;
    __builtin_amdgcn_s_setprio(1);
#pragma unroll
    for (int ks = 0; ks < 8; ks++) aS = mfma32(cur[ks], qf[ks], aS);
    __builtin_amdgcn_s_setprio(0);

    if (t + 1 < nt) {
      const u16* kp = kbase + (long)(t + 1) * 4096;
#pragma unroll
      for (int f = 0; f < 8; f++) nxt[f] = *(const bf16x8*)(kp + f * 512);
    }

    float v[16];
    const bool needmask = (t == (qrow0 >> 5));
#pragma unroll
    for (int rg = 0; rg < 4; rg++)
#pragma unroll
      for (int j = 0; j < 4; j++) {
        v[rg * 4 + j] = fmaf(aS[rg * 4 + j], SCALE_, am[rg][j]);
        if (needmask && (rg * 8 + hi * 4 + j > lr5)) v[rg * 4 + j] = -1e30f;
      }
    float mx = v[0];
#pragma unroll
    for (int i = 1; i < 16; i++) mx = fmaxf(mx, v[i]);
    mx = fmaxf(mx, __shfl_xor(mx, 32));

    if (!__all(mx <= mrun + 8.0f)) {
      float mnew = fmaxf(mrun, mx);
      float corr = __expf(mrun - mnew);
      lrun *= corr;
      mrun = mnew;
#pragma unroll
      for (int reg = 0; reg < 16; reg++) {
        float cb = __shfl(corr, (reg & 3) + 8 * (reg >> 2) + 4 * hi);
#pragma unroll
        for (int db = 0; db < 4; db++) aO[db][reg] *= cb;
      }
    }

    float ls = 0.f;
#pragma unroll
    for (int i = 0; i < 16; i++) { v[i] = __expf(v[i] - mrun); ls += v[i]; }
    ls += __shfl_xor(ls, 32);
    lrun += ls;

    unsigned pk[8];
#pragma unroll
    for (int q = 0; q < 8; q++) pk[q] = cvt_pk_bf16(v[2 * q], v[2 * q + 1]);
    bf16x8 pa[2];
#pragma unroll
    for (int kst = 0; kst < 2; kst++) {
      unsigned a0 = pk[4 * kst], a1 = pk[4 * kst + 1], a2 = pk[4 * kst + 2], a3 = pk[4 * kst + 3];
      unsigned s0 = hi ? a0 : a2;
      unsigned s1 = hi ? a1 : a3;
      unsigned r0 = __shfl_xor(s0, 32);
      unsigned r1 = __shfl_xor(s1, 32);
      union { unsigned u[4]; bf16x8 vv; } U;
      U.u[0] = hi ? r0 : a0;
      U.u[1] = hi ? r1 : a1;
      U.u[2] = hi ? a2 : r0;
      U.u[3] = hi ? a3 : r1;
      pa[kst] = U.vv;
    }

    __builtin_amdgcn_s_setprio(1);
#pragma unroll
    for (int kst = 0; kst < 2; kst++)
#pragma unroll
      for (int db = 0; db < 4; db++)
        aO[db] = mfma32(pa[kst], vf[kst * 4 + db], aO[db]);
    __builtin_amdgcn_s_setprio(0);
  };

  for (int t = 0; t < nt; t += 2) {
    body(kA, kB, t);
    if (t + 1 < nt) body(kB, kA, t + 1);
  }

  float inv = 1.0f / lrun;
#pragma unroll
  for (int reg = 0; reg < 16; reg++) {
    int r = (reg & 3) + 8 * (reg >> 2) + 4 * hi;
    float ib = __shfl(inv, r);
    int srow = qrow0 + r;
#pragma unroll
    for (int db = 0; db < 4; db++)
      ctx[(long)(b * S_ + srow) * D_ + h * HD_ + db * 32 + lr5] = f2bf(aO[db][reg] * ib);
  }
}

extern "C" void kernel_launch(void* const* d_in, const int* in_sizes, int n_in,
                              void* d_out, int out_size, void* d_ws, size_t ws_size,
                              hipStream_t stream) {
  const float* x  = (const float*)d_in[0];
  const float* am = (const float*)d_in[1];
  const float* wq = (const float*)d_in[2];
  const float* bq = (const float*)d_in[3];
  const float* wd = (const float*)d_in[4];
  const float* bd = (const float*)d_in[5];
  float* out = (float*)d_out;
  char* ws = (char*)d_ws;

  // workspace layout (88 MB peak, overlaid):
  const size_t MB = 1048576;
  u16* xb   = (u16*)(ws);                  // [4096][2048] bf16 @0   (cast -> QKV GEMM)
  u16* wqT  = (u16*)(ws + 16 * MB);        // [6144][2048] bf16 @16  (-> QKV GEMM)
  u16* qb   = (u16*)(ws + 40 * MB);        // [4096][2048] bf16 @40  (GEMM -> attn)
  u16* kpk  = (u16*)(ws + 56 * MB);        // packed K @56           (GEMM -> attn)
  u16* vpk  = (u16*)(ws + 72 * MB);        // packed V @72           (GEMM -> attn)
  u16* ctxb = (u16*)(ws);                  // [4096][2048] bf16 @0   (attn -> dense; xb dead)
  u16* wdT  = (u16*)(ws + 16 * MB);        // [2048][2048] bf16 @16  (wqT dead)

  k_cast_bf16<<<8192, 256, 0, stream>>>(x, xb, 2097152);
  k_transpose_cast<<<dim3(192, 64), dim3(32, 8), 0, stream>>>(wq, wqT, 2048, 6144);
  k_gemm8<2><<<384, 512, 0, stream>>>(xb, wqT, bq, nullptr, 4096, 6144, 2048, 16, qb, kpk, vpk);
  k_transpose_cast<<<dim3(64, 64), dim3(32, 8), 0, stream>>>(wd, wdT, 2048, 2048);
  k_attn<<<dim3(32, 16), 256, 0, stream>>>(qb, kpk, vpk, am, ctxb);
  k_gemm2<<<256, 512, 0, stream>>>(ctxb, wdT, bd, out, 4096, 2048, 2048, 16);
}

// Round 9
// 265.704 us; speedup vs baseline: 1.0200x; 1.0200x over previous
//
#include <hip/hip_runtime.h>
#include <hip/hip_bf16.h>

typedef __bf16 bf16x8 __attribute__((ext_vector_type(8)));
typedef float f32x4 __attribute__((ext_vector_type(4)));
typedef float f32x16 __attribute__((ext_vector_type(16)));
typedef unsigned short u16;

#define S_ 2048
#define D_ 2048
#define H_ 16
#define HD_ 128
#define SCALE_ 0.08838834764831845f   // 1/sqrt(128)

__device__ __forceinline__ u16 f2bf(float f) {
  unsigned u = __builtin_bit_cast(unsigned, f);
  u += 0x7fffu + ((u >> 16) & 1u);    // RNE
  return (u16)(u >> 16);
}

__device__ __forceinline__ void gload16(void* lds, const void* g) {
  __builtin_amdgcn_global_load_lds((const __attribute__((address_space(1))) void*)g,
                                   (__attribute__((address_space(3))) void*)lds, 16, 0, 0);
}

__device__ __forceinline__ f32x4 mfma16(bf16x8 a, bf16x8 b, f32x4 c) {
  return __builtin_amdgcn_mfma_f32_16x16x32_bf16(a, b, c, 0, 0, 0);
}
__device__ __forceinline__ f32x16 mfma32(bf16x8 a, bf16x8 b, f32x16 c) {
  return __builtin_amdgcn_mfma_f32_32x32x16_bf16(a, b, c, 0, 0, 0);
}

__device__ __forceinline__ unsigned cvt_pk_bf16(float lo, float hi) {
  unsigned r;
  asm("v_cvt_pk_bf16_f32 %0, %1, %2" : "=v"(r) : "v"(lo), "v"(hi));
  return r;
}

// ---------------- cast f32 -> bf16, vectorized ----------------
__global__ void k_cast_bf16(const float* __restrict__ in, u16* __restrict__ out, int n4) {
  int i = blockIdx.x * blockDim.x + threadIdx.x;
  if (i < n4) {
    float4 v = ((const float4*)in)[i];
    ushort4 o;
    o.x = f2bf(v.x); o.y = f2bf(v.y); o.z = f2bf(v.z); o.w = f2bf(v.w);
    ((ushort4*)out)[i] = o;
  }
}

// ------------- transpose + cast: in[rows][cols] f32 -> out[cols][rows] bf16 -------------
__global__ void k_transpose_cast(const float* __restrict__ in, u16* __restrict__ out,
                                 int rows, int cols) {
  __shared__ u16 tile[32][33];
  int c0 = blockIdx.x * 32, r0 = blockIdx.y * 32;
  int tx = threadIdx.x, ty = threadIdx.y;   // (32,8)
#pragma unroll
  for (int i = 0; i < 4; i++) {
    int r = r0 + ty + i * 8;
    tile[ty + i * 8][tx] = f2bf(in[(long)r * cols + c0 + tx]);
  }
  __syncthreads();
#pragma unroll
  for (int i = 0; i < 4; i++) {
    int c = c0 + ty + i * 8;
    out[(long)c * rows + r0 + tx] = tile[tx][ty + i * 8];
  }
}

// QKV scatter-store: Q -> qb[4096][2048]; K/V -> fragment-packed per-(bh,tile32) layouts
__device__ __forceinline__ void qkv_store(u16* __restrict__ qb, u16* __restrict__ kpk,
                                          u16* __restrict__ vpk, int row, int col, float val) {
  u16 o = f2bf(val);
  int h = col / 384;
  int m3 = col - h * 384;
  int b = row >> 11, s = row & 2047;
  int bh = b * 16 + h, t = s >> 5;
  if (m3 < 128) {
    qb[(long)row * 2048 + h * 128 + m3] = o;
  } else if (m3 < 256) {
    int dd = m3 - 128;
    long idx = ((((long)bh * 64 + t) * 8 + (dd >> 4)) * 64 + (((dd >> 3) & 1) << 5) + (s & 31)) * 8 + (dd & 7);
    kpk[idx] = o;
  } else {
    int dd = m3 - 256;
    long idx = ((((long)bh * 64 + t) * 8 + (((s >> 4) & 1) << 2) + (dd >> 5)) * 64 + (((s >> 3) & 1) << 5) + (dd & 31)) * 8 + (s & 7);
    vpk[idx] = o;
  }
}

// ------------- pipelined 2-phase GEMM: C[M][N] = A[M][K]*Bt[N][K]^T + bias -------------
// 256(M)x128(N) tile, BK=64, 512 thr = 8 waves (4m x 2n), per-wave 64x64.
// MODE 0: f32 plain out; MODE 2: QKV fragment-scatter out.
template <int MODE>
__global__ __launch_bounds__(512) void k_gemm2(const u16* __restrict__ A,
                                               const u16* __restrict__ Bt,
                                               const float* __restrict__ bias,
                                               void* __restrict__ Cv,
                                               int M, int N, int K, int NTM,
                                               u16* __restrict__ qb,
                                               u16* __restrict__ kpk,
                                               u16* __restrict__ vpk) {
  __shared__ __align__(16) u16 lA[2][256 * 64];
  __shared__ __align__(16) u16 lB[2][128 * 64];
  const int tid = threadIdx.x, w = tid >> 6, l = tid & 63;
  const int wr = w >> 1, wc = w & 1, lr = l & 15, lg = l >> 4;
  const int nwg = NTM * (N >> 7);
  const int per = nwg >> 3;
  const int wgid = ((int)blockIdx.x & 7) * per + ((int)blockIdx.x >> 3);
  const int tm = (wgid % NTM) << 8;
  const int tn = (wgid / NTM) << 7;
  const int NT = K >> 6;

  f32x4 acc[4][4];
#pragma unroll
  for (int m = 0; m < 4; m++)
#pragma unroll
    for (int n = 0; n < 4; n++) acc[m][n] = {0.f, 0.f, 0.f, 0.f};

  auto stageA = [&](int buf, int kt) {
#pragma unroll
    for (int i = 0; i < 4; i++) {
      int base = i * 512 + w * 64;
      int fl = base + l, r = fl >> 3, cg = (fl & 7) ^ (r & 7);
      gload16(&lA[buf][base * 8], &A[(long)(tm + r) * K + kt * 64 + cg * 8]);
    }
  };
  auto stageB = [&](int buf, int kt) {
#pragma unroll
    for (int i = 0; i < 2; i++) {
      int base = i * 512 + w * 64;
      int fl = base + l, r = fl >> 3, cg = (fl & 7) ^ (r & 7);
      gload16(&lB[buf][base * 8], &Bt[(long)(tn + r) * K + kt * 64 + cg * 8]);
    }
  };

  stageA(0, 0);
  stageB(0, 0);
  if (NT > 1) stageA(1, 1);
  asm volatile("s_waitcnt vmcnt(4)" ::: "memory");
  __builtin_amdgcn_s_barrier();

  for (int kt = 0; kt < NT; ++kt) {
    const int b = kt & 1;
    bf16x8 af[4][2], bfr[2][2];
#pragma unroll
    for (int m = 0; m < 4; m++)
#pragma unroll
      for (int k = 0; k < 2; k++) {
        int r = wr * 64 + m * 16 + lr;
        af[m][k] = *(const bf16x8*)&lA[b][r * 64 + ((((k << 2) + lg) ^ (r & 7)) << 3)];
      }
#pragma unroll
    for (int n = 0; n < 2; n++)
#pragma unroll
      for (int k = 0; k < 2; k++) {
        int r = wc * 64 + n * 16 + lr;
        bfr[n][k] = *(const bf16x8*)&lB[b][r * 64 + ((((k << 2) + lg) ^ (r & 7)) << 3)];
      }
    if (kt + 1 < NT) stageB(b ^ 1, kt + 1);
    __builtin_amdgcn_s_barrier();
    asm volatile("s_waitcnt lgkmcnt(0)" ::: "memory");
    __builtin_amdgcn_sched_barrier(0);
    __builtin_amdgcn_s_setprio(1);
#pragma unroll
    for (int m = 0; m < 4; m++)
#pragma unroll
      for (int n = 0; n < 2; n++)
#pragma unroll
        for (int k = 0; k < 2; k++)
          acc[m][n] = mfma16(af[m][k], bfr[n][k], acc[m][n]);
    __builtin_amdgcn_s_setprio(0);
    __builtin_amdgcn_s_barrier();

#pragma unroll
    for (int n = 0; n < 2; n++)
#pragma unroll
      for (int k = 0; k < 2; k++) {
        int r = wc * 64 + (n + 2) * 16 + lr;
        bfr[n][k] = *(const bf16x8*)&lB[b][r * 64 + ((((k << 2) + lg) ^ (r & 7)) << 3)];
      }
    if (kt + 2 < NT) stageA(b, kt + 2);
    __builtin_amdgcn_s_barrier();
    if (kt + 2 < NT)
      asm volatile("s_waitcnt vmcnt(4) lgkmcnt(0)" ::: "memory");
    else
      asm volatile("s_waitcnt vmcnt(0) lgkmcnt(0)" ::: "memory");
    __builtin_amdgcn_sched_barrier(0);
    __builtin_amdgcn_s_setprio(1);
#pragma unroll
    for (int m = 0; m < 4; m++)
#pragma unroll
      for (int n = 0; n < 2; n++)
#pragma unroll
        for (int k = 0; k < 2; k++)
          acc[m][n + 2] = mfma16(af[m][k], bfr[n][k], acc[m][n + 2]);
    __builtin_amdgcn_s_setprio(0);
    __builtin_amdgcn_s_barrier();
  }

#pragma unroll
  for (int n = 0; n < 4; n++) {
    int col = tn + wc * 64 + n * 16 + lr;
    float bv = bias[col];
#pragma unroll
    for (int m = 0; m < 4; m++) {
      int row0 = tm + wr * 64 + m * 16 + lg * 4;
#pragma unroll
      for (int j = 0; j < 4; j++) {
        float v = acc[m][n][j] + bv;
        if constexpr (MODE == 2)
          qkv_store(qb, kpk, vpk, row0 + j, col, v);
        else
          ((float*)Cv)[(long)(row0 + j) * N + col] = v;
      }
    }
  }
}

// ------------- causal flash attention: balanced pair-per-wave, packed fragments -------------
// grid (bh=32, pp=8), 256 thr = 4 independent waves. Wave w handles pair p = pp*4+w:
// sequentially processes q-chunk 63-p (64-p tiles) then chunk p (p+1 tiles) -> EVERY wave
// does exactly 65 tile-units; all 256 blocks uniform -> no makespan inflation.
// K/V from fragment-packed buffers (1KB coalesced frag loads), K reg-double-buffered,
// V issued early (covered by QK+softmax). No LDS, no barriers.
__global__ __launch_bounds__(256, 2) void k_attn(const u16* __restrict__ qb,
                                                 const u16* __restrict__ kpk,
                                                 const u16* __restrict__ vpk,
                                                 const float* __restrict__ amask,
                                                 u16* __restrict__ ctx) {
  const int bh = blockIdx.x, b = bh >> 4, h = bh & 15;
  const int tid = threadIdx.x, w = tid >> 6, l = tid & 63;
  const int lr5 = l & 31, hi = l >> 5;
  const int p = blockIdx.y * 4 + w;           // pair index 0..31

  const u16* kbase = kpk + (long)bh * 64 * 8 * 512 + l * 8;
  const u16* vbase = vpk + (long)bh * 64 * 8 * 512 + l * 8;
  const float* ab0 = amask + b * S_;

  auto process = [&](int c) {                 // q-chunk c: rows [32c, 32c+32), nt = c+1
    const int qrow0 = c << 5;
    const int nt = c + 1;

    bf16x8 qf[8];
    {
      const u16* qp = qb + (long)(b * S_ + qrow0 + lr5) * 2048 + h * HD_ + hi * 8;
#pragma unroll
      for (int ks = 0; ks < 8; ks++) qf[ks] = *(const bf16x8*)(qp + ks * 16);
    }

    f32x16 aO[4];
#pragma unroll
    for (int db = 0; db < 4; db++)
#pragma unroll
      for (int r = 0; r < 16; r++) aO[db][r] = 0.f;
    float mrun = -3.0e38f, lrun = 0.f;

    bf16x8 kA[8], kB[8];
#pragma unroll
    for (int f = 0; f < 8; f++) kA[f] = *(const bf16x8*)(kbase + f * 512);

    auto body = [&](bf16x8 (&cur)[8], bf16x8 (&nxt)[8], int t) {
      const int t32 = t << 5;
      bf16x8 vf[8];
      {
        const u16* vp = vbase + (long)t * 4096;
#pragma unroll
        for (int f = 0; f < 8; f++) vf[f] = *(const bf16x8*)(vp + f * 512);
      }
      f32x4 am[4];
#pragma unroll
      for (int rg = 0; rg < 4; rg++) am[rg] = *(const f32x4*)(ab0 + t32 + rg * 8 + hi * 4);

      f32x16 aS;
#pragma unroll
      for (int r = 0; r < 16; r++) aS[r] = 0.f;
      __builtin_amdgcn_s_setprio(1);
#pragma unroll
      for (int ks = 0; ks < 8; ks++) aS = mfma32(cur[ks], qf[ks], aS);
      __builtin_amdgcn_s_setprio(0);

      if (t + 1 < nt) {
        const u16* kp = kbase + (long)(t + 1) * 4096;
#pragma unroll
        for (int f = 0; f < 8; f++) nxt[f] = *(const bf16x8*)(kp + f * 512);
      }

      float v[16];
      const bool needmask = (t == c);
#pragma unroll
      for (int rg = 0; rg < 4; rg++)
#pragma unroll
        for (int j = 0; j < 4; j++) {
          v[rg * 4 + j] = fmaf(aS[rg * 4 + j], SCALE_, am[rg][j]);
          if (needmask && (rg * 8 + hi * 4 + j > lr5)) v[rg * 4 + j] = -1e30f;
        }
      float mx = v[0];
#pragma unroll
      for (int i = 1; i < 16; i++) mx = fmaxf(mx, v[i]);
      mx = fmaxf(mx, __shfl_xor(mx, 32));

      if (!__all(mx <= mrun + 8.0f)) {        // defer-max (T13)
        float mnew = fmaxf(mrun, mx);
        float corr = __expf(mrun - mnew);
        lrun *= corr;
        mrun = mnew;
#pragma unroll
        for (int reg = 0; reg < 16; reg++) {
          float cb = __shfl(corr, (reg & 3) + 8 * (reg >> 2) + 4 * hi);
#pragma unroll
          for (int db = 0; db < 4; db++) aO[db][reg] *= cb;
        }
      }

      float ls = 0.f;
#pragma unroll
      for (int i = 0; i < 16; i++) { v[i] = __expf(v[i] - mrun); ls += v[i]; }
      ls += __shfl_xor(ls, 32);
      lrun += ls;

      unsigned pk[8];
#pragma unroll
      for (int q = 0; q < 8; q++) pk[q] = cvt_pk_bf16(v[2 * q], v[2 * q + 1]);
      bf16x8 pa[2];
#pragma unroll
      for (int kst = 0; kst < 2; kst++) {
        unsigned a0 = pk[4 * kst], a1 = pk[4 * kst + 1], a2 = pk[4 * kst + 2], a3 = pk[4 * kst + 3];
        unsigned s0 = hi ? a0 : a2;
        unsigned s1 = hi ? a1 : a3;
        unsigned r0 = __shfl_xor(s0, 32);
        unsigned r1 = __shfl_xor(s1, 32);
        union { unsigned u[4]; bf16x8 vv; } U;
        U.u[0] = hi ? r0 : a0;
        U.u[1] = hi ? r1 : a1;
        U.u[2] = hi ? a2 : r0;
        U.u[3] = hi ? a3 : r1;
        pa[kst] = U.vv;
      }

      __builtin_amdgcn_s_setprio(1);
#pragma unroll
      for (int kst = 0; kst < 2; kst++)
#pragma unroll
        for (int db = 0; db < 4; db++)
          aO[db] = mfma32(pa[kst], vf[kst * 4 + db], aO[db]);
      __builtin_amdgcn_s_setprio(0);
    };

    for (int t = 0; t < nt; t += 2) {
      body(kA, kB, t);
      if (t + 1 < nt) body(kB, kA, t + 1);
    }

    float inv = 1.0f / lrun;
#pragma unroll
    for (int reg = 0; reg < 16; reg++) {
      int r = (reg & 3) + 8 * (reg >> 2) + 4 * hi;
      float ib = __shfl(inv, r);
      int srow = qrow0 + r;
#pragma unroll
      for (int db = 0; db < 4; db++)
        ctx[(long)(b * S_ + srow) * D_ + h * HD_ + db * 32 + lr5] = f2bf(aO[db][reg] * ib);
    }
  };

  process(63 - p);   // long chunk (64-p tiles)
  process(p);        // short chunk (p+1 tiles)   -> total 65 per wave
}

extern "C" void kernel_launch(void* const* d_in, const int* in_sizes, int n_in,
                              void* d_out, int out_size, void* d_ws, size_t ws_size,
                              hipStream_t stream) {
  const float* x  = (const float*)d_in[0];
  const float* am = (const float*)d_in[1];
  const float* wq = (const float*)d_in[2];
  const float* bq = (const float*)d_in[3];
  const float* wd = (const float*)d_in[4];
  const float* bd = (const float*)d_in[5];
  float* out = (float*)d_out;
  char* ws = (char*)d_ws;

  // workspace layout (88 MB peak, overlaid):
  const size_t MB = 1048576;
  u16* xb   = (u16*)(ws);                  // [4096][2048] bf16 @0   (cast -> QKV GEMM)
  u16* wqT  = (u16*)(ws + 16 * MB);        // [6144][2048] bf16 @16  (-> QKV GEMM)
  u16* qb   = (u16*)(ws + 40 * MB);        // [4096][2048] bf16 @40  (GEMM -> attn)
  u16* kpk  = (u16*)(ws + 56 * MB);        // packed K @56           (GEMM -> attn)
  u16* vpk  = (u16*)(ws + 72 * MB);        // packed V @72           (GEMM -> attn)
  u16* ctxb = (u16*)(ws);                  // [4096][2048] bf16 @0   (attn -> dense; xb dead)
  u16* wdT  = (u16*)(ws + 16 * MB);        // [2048][2048] bf16 @16  (wqT dead)

  k_cast_bf16<<<8192, 256, 0, stream>>>(x, xb, 2097152);
  k_transpose_cast<<<dim3(192, 64), dim3(32, 8), 0, stream>>>(wq, wqT, 2048, 6144);
  k_gemm2<2><<<768, 512, 0, stream>>>(xb, wqT, bq, nullptr, 4096, 6144, 2048, 16, qb, kpk, vpk);
  k_transpose_cast<<<dim3(64, 64), dim3(32, 8), 0, stream>>>(wd, wdT, 2048, 2048);
  k_attn<<<dim3(32, 8), 256, 0, stream>>>(qb, kpk, vpk, am, ctxb);
  k_gemm2<0><<<256, 512, 0, stream>>>(ctxb, wdT, bd, out, 4096, 2048, 2048, 16,
                                      nullptr, nullptr, nullptr);
}

// Round 10
// 260.525 us; speedup vs baseline: 1.0402x; 1.0199x over previous
//
#include <hip/hip_runtime.h>
#include <hip/hip_bf16.h>

typedef __bf16 bf16x8 __attribute__((ext_vector_type(8)));
typedef float f32x4 __attribute__((ext_vector_type(4)));
typedef float f32x16 __attribute__((ext_vector_type(16)));
typedef unsigned short u16;

#define S_ 2048
#define D_ 2048
#define H_ 16
#define HD_ 128
#define SCALE_ 0.08838834764831845f   // 1/sqrt(128)

__device__ __forceinline__ u16 f2bf(float f) {
  unsigned u = __builtin_bit_cast(unsigned, f);
  u += 0x7fffu + ((u >> 16) & 1u);    // RNE
  return (u16)(u >> 16);
}

__device__ __forceinline__ void gload16(void* lds, const void* g) {
  __builtin_amdgcn_global_load_lds((const __attribute__((address_space(1))) void*)g,
                                   (__attribute__((address_space(3))) void*)lds, 16, 0, 0);
}

__device__ __forceinline__ f32x4 mfma16(bf16x8 a, bf16x8 b, f32x4 c) {
  return __builtin_amdgcn_mfma_f32_16x16x32_bf16(a, b, c, 0, 0, 0);
}
__device__ __forceinline__ f32x16 mfma32(bf16x8 a, bf16x8 b, f32x16 c) {
  return __builtin_amdgcn_mfma_f32_32x32x16_bf16(a, b, c, 0, 0, 0);
}

__device__ __forceinline__ unsigned cvt_pk_bf16(float lo, float hi) {
  unsigned r;
  asm("v_cvt_pk_bf16_f32 %0, %1, %2" : "=v"(r) : "v"(lo), "v"(hi));
  return r;
}

// ---------------- cast f32 -> bf16, vectorized ----------------
__global__ void k_cast_bf16(const float* __restrict__ in, u16* __restrict__ out, int n4) {
  int i = blockIdx.x * blockDim.x + threadIdx.x;
  if (i < n4) {
    float4 v = ((const float4*)in)[i];
    ushort4 o;
    o.x = f2bf(v.x); o.y = f2bf(v.y); o.z = f2bf(v.z); o.w = f2bf(v.w);
    ((ushort4*)out)[i] = o;
  }
}

// ------------- transpose + cast: in[rows][cols] f32 -> out[cols][rows] bf16 -------------
__global__ void k_transpose_cast(const float* __restrict__ in, u16* __restrict__ out,
                                 int rows, int cols) {
  __shared__ u16 tile[32][33];
  int c0 = blockIdx.x * 32, r0 = blockIdx.y * 32;
  int tx = threadIdx.x, ty = threadIdx.y;   // (32,8)
#pragma unroll
  for (int i = 0; i < 4; i++) {
    int r = r0 + ty + i * 8;
    tile[ty + i * 8][tx] = f2bf(in[(long)r * cols + c0 + tx]);
  }
  __syncthreads();
#pragma unroll
  for (int i = 0; i < 4; i++) {
    int c = c0 + ty + i * 8;
    out[(long)c * rows + r0 + tx] = tile[tx][ty + i * 8];
  }
}

// QKV scatter-store: Q -> qb[4096][2048]; K/V -> fragment-packed per-(bh,tile32) layouts
__device__ __forceinline__ void qkv_store(u16* __restrict__ qb, u16* __restrict__ kpk,
                                          u16* __restrict__ vpk, int row, int col, float val) {
  u16 o = f2bf(val);
  int h = col / 384;
  int m3 = col - h * 384;
  int b = row >> 11, s = row & 2047;
  int bh = b * 16 + h, t = s >> 5;
  if (m3 < 128) {
    qb[(long)row * 2048 + h * 128 + m3] = o;
  } else if (m3 < 256) {
    int dd = m3 - 128;
    long idx = ((((long)bh * 64 + t) * 8 + (dd >> 4)) * 64 + (((dd >> 3) & 1) << 5) + (s & 31)) * 8 + (dd & 7);
    kpk[idx] = o;
  } else {
    int dd = m3 - 256;
    long idx = ((((long)bh * 64 + t) * 8 + (((s >> 4) & 1) << 2) + (dd >> 5)) * 64 + (((s >> 3) & 1) << 5) + (dd & 31)) * 8 + (s & 7);
    vpk[idx] = o;
  }
}

// ------------- 128x128-tile 2-phase pipelined GEMM: C = A[M][K]*Bt[N][K]^T + bias -------------
// 256 thr = 4 waves (2m x 2n), per-wave 64x64, BK=64.
// LDS 64 KB (2 bufs x (A 16KB + B 16KB)) -> 2 independent blocks/CU: cross-block wave
// overlap hides each block's barrier drains (the m97 mechanism, with conflict-free
// 128B-row chunk^(row&7) swizzle and counted vmcnt).
// Schedule per K-tile t (buf b): ph1{read af+bf01(b); stage B(t+1)->b^1; bar; lgkm0; 16 MFMA; bar}
//                                ph2{read bf23(b); stage A(t+2)->b(A dead); bar; vmcnt(4); 16 MFMA; bar}
// Steady-state outstanding at ph2-wait: A(t+1)[4] B(t+1)[4] A(t+2)[4] -> vmcnt(4) retires A(t+1),B(t+1).
template <int MODE>   // 2: QKV fragment-scatter out; 0: f32 out
__global__ __launch_bounds__(256, 2) void k_gemm(const u16* __restrict__ A,
                                                 const u16* __restrict__ Bt,
                                                 const float* __restrict__ bias,
                                                 void* __restrict__ Cv,
                                                 int M, int N, int K, int NTM,
                                                 u16* __restrict__ qb,
                                                 u16* __restrict__ kpk,
                                                 u16* __restrict__ vpk) {
  __shared__ __align__(16) u16 lA[2][128 * 64];
  __shared__ __align__(16) u16 lB[2][128 * 64];
  const int tid = threadIdx.x, w = tid >> 6, l = tid & 63;
  const int wm = w >> 1, wn = w & 1, lr = l & 15, lg = l >> 4;
  const int nwg = NTM * (N >> 7);
  const int per = nwg >> 3;                     // nwg % 8 == 0
  const int wgid = ((int)blockIdx.x & 7) * per + ((int)blockIdx.x >> 3);
  const int tm = (wgid % NTM) << 7;
  const int tn = (wgid / NTM) << 7;
  const int NT = K >> 6;

  f32x4 acc[4][4];
#pragma unroll
  for (int m = 0; m < 4; m++)
#pragma unroll
    for (int n = 0; n < 4; n++) acc[m][n] = {0.f, 0.f, 0.f, 0.f};

  // stage 128x64 tile = 1024 chunks; 4 gload16/thread, wave-uniform dest bases
  auto stageA = [&](int buf, int kt) {
#pragma unroll
    for (int i = 0; i < 4; i++) {
      int base = i * 256 + w * 64;
      int f = base + l, r = f >> 3, cg = (f & 7) ^ (r & 7);
      gload16(&lA[buf][base * 8], &A[(long)(tm + r) * K + kt * 64 + cg * 8]);
    }
  };
  auto stageB = [&](int buf, int kt) {
#pragma unroll
    for (int i = 0; i < 4; i++) {
      int base = i * 256 + w * 64;
      int f = base + l, r = f >> 3, cg = (f & 7) ^ (r & 7);
      gload16(&lB[buf][base * 8], &Bt[(long)(tn + r) * K + kt * 64 + cg * 8]);
    }
  };

  // prologue: A(0),B(0) -> buf0; A(1) -> buf1; retire tile0, leave A(1) in flight
  stageA(0, 0);
  stageB(0, 0);
  if (NT > 1) stageA(1, 1);
  asm volatile("s_waitcnt vmcnt(4)" ::: "memory");
  __builtin_amdgcn_s_barrier();

  for (int kt = 0; kt < NT; ++kt) {
    const int b = kt & 1;
    bf16x8 af[4][2], bfr[2][2];
    // ---- phase 1: all A-frags + B n-frags 0,1 ----
#pragma unroll
    for (int m = 0; m < 4; m++)
#pragma unroll
      for (int k = 0; k < 2; k++) {
        int r = wm * 64 + m * 16 + lr;
        af[m][k] = *(const bf16x8*)&lA[b][r * 64 + ((((k << 2) + lg) ^ (r & 7)) << 3)];
      }
#pragma unroll
    for (int n = 0; n < 2; n++)
#pragma unroll
      for (int k = 0; k < 2; k++) {
        int r = wn * 64 + n * 16 + lr;
        bfr[n][k] = *(const bf16x8*)&lB[b][r * 64 + ((((k << 2) + lg) ^ (r & 7)) << 3)];
      }
    if (kt + 1 < NT) stageB(b ^ 1, kt + 1);
    __builtin_amdgcn_s_barrier();
    asm volatile("s_waitcnt lgkmcnt(0)" ::: "memory");
    __builtin_amdgcn_sched_barrier(0);
    __builtin_amdgcn_s_setprio(1);
#pragma unroll
    for (int m = 0; m < 4; m++)
#pragma unroll
      for (int n = 0; n < 2; n++)
#pragma unroll
        for (int k = 0; k < 2; k++)
          acc[m][n] = mfma16(af[m][k], bfr[n][k], acc[m][n]);
    __builtin_amdgcn_s_setprio(0);
    __builtin_amdgcn_s_barrier();

    // ---- phase 2: B n-frags 2,3; stage A(t+2) into current buf's dead A-region ----
#pragma unroll
    for (int n = 0; n < 2; n++)
#pragma unroll
      for (int k = 0; k < 2; k++) {
        int r = wn * 64 + (n + 2) * 16 + lr;
        bfr[n][k] = *(const bf16x8*)&lB[b][r * 64 + ((((k << 2) + lg) ^ (r & 7)) << 3)];
      }
    if (kt + 2 < NT) stageA(b, kt + 2);
    __builtin_amdgcn_s_barrier();
    if (kt + 2 < NT)
      asm volatile("s_waitcnt vmcnt(4) lgkmcnt(0)" ::: "memory");
    else
      asm volatile("s_waitcnt vmcnt(0) lgkmcnt(0)" ::: "memory");
    __builtin_amdgcn_sched_barrier(0);
    __builtin_amdgcn_s_setprio(1);
#pragma unroll
    for (int m = 0; m < 4; m++)
#pragma unroll
      for (int n = 0; n < 2; n++)
#pragma unroll
        for (int k = 0; k < 2; k++)
          acc[m][n + 2] = mfma16(af[m][k], bfr[n][k], acc[m][n + 2]);
    __builtin_amdgcn_s_setprio(0);
    __builtin_amdgcn_s_barrier();
  }

  // epilogue
#pragma unroll
  for (int n = 0; n < 4; n++) {
    int col = tn + wn * 64 + n * 16 + lr;
    float bv = bias[col];
#pragma unroll
    for (int m = 0; m < 4; m++) {
      int row0 = tm + wm * 64 + m * 16 + lg * 4;
#pragma unroll
      for (int j = 0; j < 4; j++) {
        float v = acc[m][n][j] + bv;
        if constexpr (MODE == 2)
          qkv_store(qb, kpk, vpk, row0 + j, col, v);
        else
          ((float*)Cv)[(long)(row0 + j) * N + col] = v;
      }
    }
  }
}

// ------------- causal flash attention: balanced pair-per-wave, packed fragments -------------
// grid (bh=32, pp=8), 256 thr = 4 independent waves. Wave w handles pair p = pp*4+w:
// chunk 63-p then chunk p -> every wave exactly 65 tile-units. K/V from fragment-packed
// buffers (1KB coalesced frag loads), K reg-double-buffered, V issued early. No LDS/barriers.
__global__ __launch_bounds__(256, 2) void k_attn(const u16* __restrict__ qb,
                                                 const u16* __restrict__ kpk,
                                                 const u16* __restrict__ vpk,
                                                 const float* __restrict__ amask,
                                                 u16* __restrict__ ctx) {
  const int bh = blockIdx.x, b = bh >> 4, h = bh & 15;
  const int tid = threadIdx.x, w = tid >> 6, l = tid & 63;
  const int lr5 = l & 31, hi = l >> 5;
  const int p = blockIdx.y * 4 + w;           // pair index 0..31

  const u16* kbase = kpk + (long)bh * 64 * 8 * 512 + l * 8;
  const u16* vbase = vpk + (long)bh * 64 * 8 * 512 + l * 8;
  const float* ab0 = amask + b * S_;

  auto process = [&](int c) {                 // q-chunk c: rows [32c, 32c+32), nt = c+1
    const int qrow0 = c << 5;
    const int nt = c + 1;

    bf16x8 qf[8];
    {
      const u16* qp = qb + (long)(b * S_ + qrow0 + lr5) * 2048 + h * HD_ + hi * 8;
#pragma unroll
      for (int ks = 0; ks < 8; ks++) qf[ks] = *(const bf16x8*)(qp + ks * 16);
    }

    f32x16 aO[4];
#pragma unroll
    for (int db = 0; db < 4; db++)
#pragma unroll
      for (int r = 0; r < 16; r++) aO[db][r] = 0.f;
    float mrun = -3.0e38f, lrun = 0.f;

    bf16x8 kA[8], kB[8];
#pragma unroll
    for (int f = 0; f < 8; f++) kA[f] = *(const bf16x8*)(kbase + f * 512);

    auto body = [&](bf16x8 (&cur)[8], bf16x8 (&nxt)[8], int t) {
      const int t32 = t << 5;
      bf16x8 vf[8];
      {
        const u16* vp = vbase + (long)t * 4096;
#pragma unroll
        for (int f = 0; f < 8; f++) vf[f] = *(const bf16x8*)(vp + f * 512);
      }
      f32x4 am[4];
#pragma unroll
      for (int rg = 0; rg < 4; rg++) am[rg] = *(const f32x4*)(ab0 + t32 + rg * 8 + hi * 4);

      f32x16 aS;
#pragma unroll
      for (int r = 0; r < 16; r++) aS[r] = 0.f;
      __builtin_amdgcn_s_setprio(1);
#pragma unroll
      for (int ks = 0; ks < 8; ks++) aS = mfma32(cur[ks], qf[ks], aS);
      __builtin_amdgcn_s_setprio(0);

      if (t + 1 < nt) {
        const u16* kp = kbase + (long)(t + 1) * 4096;
#pragma unroll
        for (int f = 0; f < 8; f++) nxt[f] = *(const bf16x8*)(kp + f * 512);
      }

      float v[16];
      const bool needmask = (t == c);
#pragma unroll
      for (int rg = 0; rg < 4; rg++)
#pragma unroll
        for (int j = 0; j < 4; j++) {
          v[rg * 4 + j] = fmaf(aS[rg * 4 + j], SCALE_, am[rg][j]);
          if (needmask && (rg * 8 + hi * 4 + j > lr5)) v[rg * 4 + j] = -1e30f;
        }
      float mx = v[0];
#pragma unroll
      for (int i = 1; i < 16; i++) mx = fmaxf(mx, v[i]);
      mx = fmaxf(mx, __shfl_xor(mx, 32));

      if (!__all(mx <= mrun + 8.0f)) {        // defer-max (T13)
        float mnew = fmaxf(mrun, mx);
        float corr = __expf(mrun - mnew);
        lrun *= corr;
        mrun = mnew;
#pragma unroll
        for (int reg = 0; reg < 16; reg++) {
          float cb = __shfl(corr, (reg & 3) + 8 * (reg >> 2) + 4 * hi);
#pragma unroll
          for (int db = 0; db < 4; db++) aO[db][reg] *= cb;
        }
      }

      float ls = 0.f;
#pragma unroll
      for (int i = 0; i < 16; i++) { v[i] = __expf(v[i] - mrun); ls += v[i]; }
      ls += __shfl_xor(ls, 32);
      lrun += ls;

      unsigned pk[8];
#pragma unroll
      for (int q = 0; q < 8; q++) pk[q] = cvt_pk_bf16(v[2 * q], v[2 * q + 1]);
      bf16x8 pa[2];
#pragma unroll
      for (int kst = 0; kst < 2; kst++) {
        unsigned a0 = pk[4 * kst], a1 = pk[4 * kst + 1], a2 = pk[4 * kst + 2], a3 = pk[4 * kst + 3];
        unsigned s0 = hi ? a0 : a2;
        unsigned s1 = hi ? a1 : a3;
        unsigned r0 = __shfl_xor(s0, 32);
        unsigned r1 = __shfl_xor(s1, 32);
        union { unsigned u[4]; bf16x8 vv; } U;
        U.u[0] = hi ? r0 : a0;
        U.u[1] = hi ? r1 : a1;
        U.u[2] = hi ? a2 : r0;
        U.u[3] = hi ? a3 : r1;
        pa[kst] = U.vv;
      }

      __builtin_amdgcn_s_setprio(1);
#pragma unroll
      for (int kst = 0; kst < 2; kst++)
#pragma unroll
        for (int db = 0; db < 4; db++)
          aO[db] = mfma32(pa[kst], vf[kst * 4 + db], aO[db]);
      __builtin_amdgcn_s_setprio(0);
    };

    for (int t = 0; t < nt; t += 2) {
      body(kA, kB, t);
      if (t + 1 < nt) body(kB, kA, t + 1);
    }

    float inv = 1.0f / lrun;
#pragma unroll
    for (int reg = 0; reg < 16; reg++) {
      int r = (reg & 3) + 8 * (reg >> 2) + 4 * hi;
      float ib = __shfl(inv, r);
      int srow = qrow0 + r;
#pragma unroll
      for (int db = 0; db < 4; db++)
        ctx[(long)(b * S_ + srow) * D_ + h * HD_ + db * 32 + lr5] = f2bf(aO[db][reg] * ib);
    }
  };

  process(63 - p);   // long chunk (64-p tiles)
  process(p);        // short chunk (p+1 tiles)   -> total 65 per wave
}

extern "C" void kernel_launch(void* const* d_in, const int* in_sizes, int n_in,
                              void* d_out, int out_size, void* d_ws, size_t ws_size,
                              hipStream_t stream) {
  const float* x  = (const float*)d_in[0];
  const float* am = (const float*)d_in[1];
  const float* wq = (const float*)d_in[2];
  const float* bq = (const float*)d_in[3];
  const float* wd = (const float*)d_in[4];
  const float* bd = (const float*)d_in[5];
  float* out = (float*)d_out;
  char* ws = (char*)d_ws;

  // workspace layout (88 MB peak, overlaid):
  const size_t MB = 1048576;
  u16* xb   = (u16*)(ws);                  // [4096][2048] bf16 @0   (cast -> QKV GEMM)
  u16* wqT  = (u16*)(ws + 16 * MB);        // [6144][2048] bf16 @16  (-> QKV GEMM)
  u16* qb   = (u16*)(ws + 40 * MB);        // [4096][2048] bf16 @40  (GEMM -> attn)
  u16* kpk  = (u16*)(ws + 56 * MB);        // packed K @56           (GEMM -> attn)
  u16* vpk  = (u16*)(ws + 72 * MB);        // packed V @72           (GEMM -> attn)
  u16* ctxb = (u16*)(ws);                  // [4096][2048] bf16 @0   (attn -> dense; xb dead)
  u16* wdT  = (u16*)(ws + 16 * MB);        // [2048][2048] bf16 @16  (wqT dead)

  k_cast_bf16<<<8192, 256, 0, stream>>>(x, xb, 2097152);
  k_transpose_cast<<<dim3(192, 64), dim3(32, 8), 0, stream>>>(wq, wqT, 2048, 6144);
  k_gemm<2><<<1536, 256, 0, stream>>>(xb, wqT, bq, nullptr, 4096, 6144, 2048, 32, qb, kpk, vpk);
  k_transpose_cast<<<dim3(64, 64), dim3(32, 8), 0, stream>>>(wd, wdT, 2048, 2048);
  k_attn<<<dim3(32, 8), 256, 0, stream>>>(qb, kpk, vpk, am, ctxb);
  k_gemm<0><<<512, 256, 0, stream>>>(ctxb, wdT, bd, out, 4096, 2048, 2048, 32,
                                     nullptr, nullptr, nullptr);
}